// Round 8
// baseline (1101.320 us; speedup 1.0000x reference)
//
#include <hip/hip_runtime.h>

#define Mc 512
#define Nc 1024
#define WRc 16
#define Bc 4096

// Layered min-sum. R8: ONE batch element per wave (lanes 0-15 active in the
// main loop), 4 waves per 256-thread block, 1024 blocks -> 4096 waves =
// 4 waves/SIMD (vs 1 before): four independent serial chains interleave on
// each SIMD, hiding the scatter->gather LDS turnaround and DPP-chain bubbles
// that dominated R6/R7 (~600 cyc/step with zero TLP).
// Per-step metadata: precomputed fused stream g_idx[s*16+j] = H[cn_order[s]][j]
// (16 KB, L1-hot). Compressed row state FIFO per wave in LDS (slot s = t mod
// 512; write t, read t+4 == written 508 steps ago):
//   stAB = (m1c, m2c) clipped min/2nd-min bits, stC = signs16|a1<<16|tp<<20
//   c2v_j = (j==a1 ? m2c : m1c) signed by (tp ^ sign_j)  [bit-exact, ties ok]
// LDS = 16K vn + 16K stAB + 8K stC = 40960 B -> 4 blocks/CU = 16 waves/CU.
// __launch_bounds__(256,4) caps VGPR at 128 so 4 waves/SIMD are resident.

__device__ unsigned short g_idx[Mc * WRc];  // fused index stream (16 KB)

#define DPPI(old, src, ctrl) \
  __builtin_amdgcn_update_dpp((old), (src), (ctrl), 0xF, 0xF, false)

static __device__ __forceinline__ int imin(int a, int b) { return a < b ? a : b; }
static __device__ __forceinline__ int imax(int a, int b) { return a > b ? a : b; }

#define CLIPB 0x41A00000  /* bits of 20.0f */
#define INFB  0x7F800000

__global__ void build_idx(const int* __restrict__ H,
                          const int* __restrict__ cn_order) {
  const int i = blockIdx.x * 1024 + threadIdx.x;   // grid 8 x 1024
  if (i < Mc * WRc)
    g_idx[i] = (unsigned short)H[cn_order[i >> 4] * WRc + (i & 15)];
}

__global__ __launch_bounds__(256, 4) void ldpc_kernel(
    const float* __restrict__ llr, const int* __restrict__ iters_p,
    float* __restrict__ out) {
  const int tid = threadIdx.x;
  const int w = tid >> 6;       // wave in block = batch sub-element (0..3)
  const int lane = tid & 63;
  const int j = lane & 15;      // edge position in the check node
  const int b0 = blockIdx.x * 4;

  __shared__ float vn[4][Nc];          // 16 KB: vn[w] is wave w's LLR state
  __shared__ uint2 stAB[4 * Mc];       // 16 KB: (m1c, m2c) per (wave, slot)
  __shared__ unsigned stC[4 * Mc];     //  8 KB: signs16 | a1<<16 | tp<<20

  // Staging: flat coalesced copy (vn[w][n] = llr[(b0+w)*Nc + n]).
  for (int i = tid; i < 4 * Nc; i += 256)
    vn[0][i] = llr[(size_t)b0 * Nc + i];
  __syncthreads();

  const int T = iters_p[0] * Mc;   // iters*512, multiple of 4

  if (lane < 16) {
    const unsigned short* const sp = g_idx + j;   // lane-const stream base
    float* const vw = vn[w];
    uint2* const fAB = stAB + w * Mc;
    unsigned* const fC = stC + w * Mc;

    // prime index queue (depth 3) + first gather
    int i0 = (int)sp[0 * WRc];
    int i1 = (int)sp[1 * WRc];
    int i2 = (int)sp[2 * WRc];
    float v = vw[i0];
    float c2vf[4] = {0.0f, 0.0f, 0.0f, 0.0f};

    const int A_end = (T >= Mc) ? (Mc - 4) : T;   // 508, mult. of 4

    int t = 0;
    // ============== Loop A: sweep 0 (c2v == 0, no FIFO reads) ==============
    for (; t < A_end; t += 4) {
#pragma unroll
      for (int k = 0; k < 4; ++k) {
        const int tt = t + k;
        const float v2c = v;                       // c2v is zero in sweep 0
        const int ab = __float_as_int(v2c) & 0x7FFFFFFF;

        int p = ab;                                // inclusive prefix-min
        p = imin(p, DPPI(INFB, p, 0x111));
        p = imin(p, DPPI(INFB, p, 0x112));
        p = imin(p, DPPI(INFB, p, 0x114));
        p = imin(p, DPPI(INFB, p, 0x118));
        int s = ab;                                // inclusive suffix-min
        s = imin(s, DPPI(INFB, s, 0x101));
        s = imin(s, DPPI(INFB, s, 0x102));
        s = imin(s, DPPI(INFB, s, 0x104));
        s = imin(s, DPPI(INFB, s, 0x108));
        const int pe = DPPI(INFB, p, 0x111);       // exclusive
        const int se = DPPI(INFB, s, 0x101);
        const int loo = imin(pe, se);              // leave-one-out min
        const int ampi = imin(loo, CLIPB);

        const unsigned sgn16 = ((unsigned)__ballot(v2c < 0.0f)) & 0xFFFFu;
        const unsigned tp = (unsigned)__popc(sgn16) & 1u;
        const unsigned sb = ((unsigned)__float_as_int(v2c)) >> 31;
        const float nc = __uint_as_float((unsigned)ampi | ((tp ^ sb) << 31));

        vw[i0] = v2c + nc;      // scatter (slot tt)
        v = vw[i1];             // gather (slot tt+1) — back-to-back

        // FIFO write (consumed one sweep later)
        const int m1 = imin(loo, ab);
        const unsigned mbal = ((unsigned)__ballot(ab == m1)) & 0xFFFFu;
        const int a1 = __ffs(mbal) - 1;
        int mx = loo;                              // m2 = max_j loo_j
        mx = imax(mx, DPPI(0, mx, 0x121));
        mx = imax(mx, DPPI(0, mx, 0x122));
        mx = imax(mx, DPPI(0, mx, 0x124));
        mx = imax(mx, DPPI(0, mx, 0x128));
        if (j == 0) {
          fAB[tt & (Mc - 1)] = make_uint2((unsigned)imin(m1, CLIPB),
                                          (unsigned)imin(mx, CLIPB));
          fC[tt & (Mc - 1)] = sgn16 | ((unsigned)a1 << 16) | (tp << 20);
        }

        i0 = i1; i1 = i2;                          // rotate index queue
        i2 = (int)sp[((tt + 3) & (Mc - 1)) * WRc];
      }
    }

    // ============== Loop B: steady state (full body) =======================
    for (; t < T; t += 4) {
#pragma unroll
      for (int k = 0; k < 4; ++k) {
        const int tt = t + k;
        const float v2c = v - c2vf[k];
        const int ab = __float_as_int(v2c) & 0x7FFFFFFF;

        int p = ab;
        p = imin(p, DPPI(INFB, p, 0x111));
        p = imin(p, DPPI(INFB, p, 0x112));
        p = imin(p, DPPI(INFB, p, 0x114));
        p = imin(p, DPPI(INFB, p, 0x118));
        int s = ab;
        s = imin(s, DPPI(INFB, s, 0x101));
        s = imin(s, DPPI(INFB, s, 0x102));
        s = imin(s, DPPI(INFB, s, 0x104));
        s = imin(s, DPPI(INFB, s, 0x108));
        const int pe = DPPI(INFB, p, 0x111);
        const int se = DPPI(INFB, s, 0x101);
        const int loo = imin(pe, se);
        const int ampi = imin(loo, CLIPB);

        const unsigned sgn16 = ((unsigned)__ballot(v2c < 0.0f)) & 0xFFFFu;
        const unsigned tp = (unsigned)__popc(sgn16) & 1u;
        const unsigned sb = ((unsigned)__float_as_int(v2c)) >> 31;
        const float nc = __uint_as_float((unsigned)ampi | ((tp ^ sb) << 31));

        vw[i0] = v2c + nc;      // scatter (slot tt)
        v = vw[i1];             // gather (slot tt+1)

        // FIFO write
        const int m1 = imin(loo, ab);
        const unsigned mbal = ((unsigned)__ballot(ab == m1)) & 0xFFFFu;
        const int a1 = __ffs(mbal) - 1;
        int mx = loo;
        mx = imax(mx, DPPI(0, mx, 0x121));
        mx = imax(mx, DPPI(0, mx, 0x122));
        mx = imax(mx, DPPI(0, mx, 0x124));
        mx = imax(mx, DPPI(0, mx, 0x128));
        if (j == 0) {
          fAB[tt & (Mc - 1)] = make_uint2((unsigned)imin(m1, CLIPB),
                                          (unsigned)imin(mx, CLIPB));
          fC[tt & (Mc - 1)] = sgn16 | ((unsigned)a1 << 16) | (tp << 20);
        }

        // FIFO read + reconstruct c2v for step tt+4 (always past sweep 0 here)
        const int rsl = (tt + 4) & (Mc - 1);
        const uint2 mm = fAB[rsl];                 // broadcast reads
        const unsigned met = fC[rsl];
        const unsigned psb = (met >> j) & 1u;
        const unsigned ptp = (met >> 20) & 1u;
        const unsigned pai = (j == (int)((met >> 16) & 15u)) ? mm.y : mm.x;
        c2vf[k] = __uint_as_float(pai | ((ptp ^ psb) << 31));

        i0 = i1; i1 = i2;                          // rotate index queue
        i2 = (int)sp[((tt + 3) & (Mc - 1)) * WRc];
      }
    }
  }
  __syncthreads();

  // Hard decision: flat coalesced store across all 4 waves' vn.
  for (int i = tid; i < 4 * Nc; i += 256)
    out[(size_t)b0 * Nc + i] = (vn[0][i] < 0.0f) ? 1.0f : 0.0f;
}

extern "C" void kernel_launch(void* const* d_in, const int* in_sizes, int n_in,
                              void* d_out, int out_size, void* d_ws, size_t ws_size,
                              hipStream_t stream) {
  const float* llr = (const float*)d_in[0];
  const int* H = (const int*)d_in[1];
  const int* iters_p = (const int*)d_in[2];
  const int* cn_order = (const int*)d_in[3];
  float* out = (float*)d_out;
  build_idx<<<dim3(8), dim3(1024), 0, stream>>>(H, cn_order);
  ldpc_kernel<<<dim3(Bc / 4), dim3(256), 0, stream>>>(llr, iters_p, out);
}

// Round 9
// 727.177 us; speedup vs baseline: 1.5145x; 1.5145x over previous
//
#include <hip/hip_runtime.h>

#define Mc 512
#define Nc 1024
#define WRc 16
#define Bc 4096

// Layered min-sum. R9 = R6 macro-config (64-thread blocks, 16 lanes x 4 batch
// elements per wave, 1 wave/SIMD, 4 blocks/CU) with the serial chain slimmed:
//  - FIFO reads land in rotating RAW registers; bit-exact reconstruction
//    (c2v_j = (j==a1?m2c:m1c) signed by tp^sign_j) is deferred 4 bodies to
//    consume time -> the lgkmcnt wait has 4 bodies of slack.
//  - on-chain sign parity via 4-stage DPP-XOR (no ballot/SALU on the chain).
//  - vn layout [Nc][4] (group-minor): the 4 groups hit distinct LDS banks.
//  - fused precomputed index stream g_idx[s*16+j] = H[cn_order[s]][j], queue
//    depth 6 (vmcnt-only, deep slack).
// LDS = 16K vn + 16K stAB + 8K stC = 40960 B -> exactly 4 blocks/CU.

__device__ unsigned short g_idx[Mc * WRc];  // fused index stream (16 KB)

#define DPPI(old, src, ctrl) \
  __builtin_amdgcn_update_dpp((old), (src), (ctrl), 0xF, 0xF, false)

static __device__ __forceinline__ int imin(int a, int b) { return a < b ? a : b; }
static __device__ __forceinline__ int imax(int a, int b) { return a > b ? a : b; }

#define CLIPB 0x41A00000  /* bits of 20.0f */
#define INFB  0x7F800000

__global__ void build_idx(const int* __restrict__ H,
                          const int* __restrict__ cn_order) {
  const int i = blockIdx.x * 1024 + threadIdx.x;   // grid 8 x 1024
  if (i < Mc * WRc)
    g_idx[i] = (unsigned short)H[cn_order[i >> 4] * WRc + (i & 15)];
}

__global__ __launch_bounds__(64) void ldpc_kernel(
    const float* __restrict__ llr, const int* __restrict__ iters_p,
    float* __restrict__ out) {
  const int tid = threadIdx.x;
  const int g = tid >> 4;    // batch sub-slot (0..3) == DPP row
  const int j = tid & 15;    // edge position in the check node
  const int b0 = blockIdx.x * 4;
  const int shft = g * 16;

  __shared__ float vn[Nc][4];          // 16 KB, group-minor: distinct banks
  __shared__ uint2 stAB[Mc * 4];       // 16 KB: (m1c, m2c) per (slot, g)
  __shared__ unsigned stC[Mc * 4];     //  8 KB: signs16 | a1<<16 | tp<<20

  for (int i = tid; i < 4 * Nc; i += 64) {
    const int gg = i >> 10, n = i & (Nc - 1);
    vn[n][gg] = llr[(size_t)(b0 + gg) * Nc + n];
  }
  __syncthreads();

  const int T = iters_p[0] * Mc;       // iters*512, multiple of 4
  const unsigned short* const sp = g_idx + j;   // lane-const stream base

  // ---- index queue depth 6 + first gather ----
  int i0 = (int)sp[0 * WRc];
  int i1 = (int)sp[1 * WRc];
  int i2 = (int)sp[2 * WRc];
  int i3 = (int)sp[3 * WRc];
  int i4 = (int)sp[4 * WRc];
  int i5 = (int)sp[5 * WRc];
  float v = vn[i0][g];

  // raw FIFO regs for steps +0..+3 of the next 4-group (reconstruct -> +0.0f)
  unsigned rm1[4] = {0, 0, 0, 0};
  unsigned rm2[4] = {0, 0, 0, 0};
  unsigned rmt[4] = {0, 0, 0, 0};

  const int A_end = (T >= Mc) ? (Mc - 4) : T;   // 508, mult. of 4

  int t = 0;
  // ============== Loop A: sweep 0 (c2v == 0, no FIFO reads) ================
  for (; t < A_end; t += 4) {
#pragma unroll
    for (int k = 0; k < 4; ++k) {
      const int tt = t + k;
      const float v2c = v;                       // c2v is zero in sweep 0
      const int ab = __float_as_int(v2c) & 0x7FFFFFFF;

      int p = ab;                                // inclusive prefix-min
      p = imin(p, DPPI(INFB, p, 0x111));
      p = imin(p, DPPI(INFB, p, 0x112));
      p = imin(p, DPPI(INFB, p, 0x114));
      p = imin(p, DPPI(INFB, p, 0x118));
      int s = ab;                                // inclusive suffix-min
      s = imin(s, DPPI(INFB, s, 0x101));
      s = imin(s, DPPI(INFB, s, 0x102));
      s = imin(s, DPPI(INFB, s, 0x104));
      s = imin(s, DPPI(INFB, s, 0x108));
      const int pe = DPPI(INFB, p, 0x111);       // exclusive
      const int se = DPPI(INFB, s, 0x101);
      const int loo = imin(pe, se);              // leave-one-out min
      const int ampi = imin(loo, CLIPB);

      // sign parity on-chain via DPP-XOR (no ballot round trip)
      const unsigned ng = ((unsigned)__float_as_int(v2c)) >> 31;
      unsigned x = ng;
      x ^= (unsigned)DPPI(0, (int)x, 0x121);
      x ^= (unsigned)DPPI(0, (int)x, 0x122);
      x ^= (unsigned)DPPI(0, (int)x, 0x124);
      x ^= (unsigned)DPPI(0, (int)x, 0x128);     // x = total parity (uniform)
      const float nc = __uint_as_float((unsigned)ampi | ((x ^ ng) << 31));

      vn[i0][g] = v2c + nc;     // scatter (slot tt)
      v = vn[i1][g];            // gather (slot tt+1) — back-to-back

      // ---- off-chain: FIFO write (consumed one sweep later) ----
      const int m1 = imin(loo, ab);              // row min (uniform)
      const unsigned sgn16 = ((unsigned)(__ballot(v2c < 0.0f) >> shft)) & 0xFFFFu;
      const unsigned mb16 = ((unsigned)(__ballot(ab == m1) >> shft)) & 0xFFFFu;
      const int a1 = __ffs(mb16) - 1;
      int mx = loo;                              // m2 = max_j loo_j
      mx = imax(mx, DPPI(0, mx, 0x121));
      mx = imax(mx, DPPI(0, mx, 0x122));
      mx = imax(mx, DPPI(0, mx, 0x124));
      mx = imax(mx, DPPI(0, mx, 0x128));
      const int wsl = (tt & (Mc - 1)) * 4 + g;
      if (j == 0) {
        stAB[wsl] = make_uint2((unsigned)imin(m1, CLIPB),
                               (unsigned)imin(mx, CLIPB));
        stC[wsl] = sgn16 | ((unsigned)a1 << 16) | (x << 20);
      }

      i0 = i1; i1 = i2; i2 = i3; i3 = i4; i4 = i5;   // rotate index queue
      i5 = (int)sp[((tt + 6) & (Mc - 1)) * WRc];
    }
  }

  // ============== Loop B: steady state ====================================
  for (; t < T; t += 4) {
#pragma unroll
    for (int k = 0; k < 4; ++k) {
      const int tt = t + k;

      // deferred reconstruct (raw regs loaded 4 bodies ago; no LDS wait here)
      const unsigned met = rmt[k];
      const unsigned psb = (met >> j) & 1u;
      const unsigned ptp = (met >> 20) & 1u;
      const unsigned pai = (j == (int)((met >> 16) & 15u)) ? rm2[k] : rm1[k];
      const float c2v = __uint_as_float(pai | ((ptp ^ psb) << 31));

      const float v2c = v - c2v;
      const int ab = __float_as_int(v2c) & 0x7FFFFFFF;

      int p = ab;
      p = imin(p, DPPI(INFB, p, 0x111));
      p = imin(p, DPPI(INFB, p, 0x112));
      p = imin(p, DPPI(INFB, p, 0x114));
      p = imin(p, DPPI(INFB, p, 0x118));
      int s = ab;
      s = imin(s, DPPI(INFB, s, 0x101));
      s = imin(s, DPPI(INFB, s, 0x102));
      s = imin(s, DPPI(INFB, s, 0x104));
      s = imin(s, DPPI(INFB, s, 0x108));
      const int pe = DPPI(INFB, p, 0x111);
      const int se = DPPI(INFB, s, 0x101);
      const int loo = imin(pe, se);
      const int ampi = imin(loo, CLIPB);

      const unsigned ng = ((unsigned)__float_as_int(v2c)) >> 31;
      unsigned x = ng;
      x ^= (unsigned)DPPI(0, (int)x, 0x121);
      x ^= (unsigned)DPPI(0, (int)x, 0x122);
      x ^= (unsigned)DPPI(0, (int)x, 0x124);
      x ^= (unsigned)DPPI(0, (int)x, 0x128);
      const float nc = __uint_as_float((unsigned)ampi | ((x ^ ng) << 31));

      vn[i0][g] = v2c + nc;     // scatter (slot tt)
      v = vn[i1][g];            // gather (slot tt+1)

      // ---- off-chain: FIFO write ----
      const int m1 = imin(loo, ab);
      const unsigned sgn16 = ((unsigned)(__ballot(v2c < 0.0f) >> shft)) & 0xFFFFu;
      const unsigned mb16 = ((unsigned)(__ballot(ab == m1) >> shft)) & 0xFFFFu;
      const int a1 = __ffs(mb16) - 1;
      int mx = loo;
      mx = imax(mx, DPPI(0, mx, 0x121));
      mx = imax(mx, DPPI(0, mx, 0x122));
      mx = imax(mx, DPPI(0, mx, 0x124));
      mx = imax(mx, DPPI(0, mx, 0x128));
      const int wsl = (tt & (Mc - 1)) * 4 + g;
      if (j == 0) {
        stAB[wsl] = make_uint2((unsigned)imin(m1, CLIPB),
                               (unsigned)imin(mx, CLIPB));
        stC[wsl] = sgn16 | ((unsigned)a1 << 16) | (x << 20);
      }

      // ---- off-chain: FIFO read for step tt+4 into raw regs (no consume) ----
      const int rsl = ((tt + 4) & (Mc - 1)) * 4 + g;
      const uint2 mm = stAB[rsl];                // broadcast reads
      rm1[k] = mm.x;
      rm2[k] = mm.y;
      rmt[k] = stC[rsl];

      i0 = i1; i1 = i2; i2 = i3; i3 = i4; i4 = i5;   // rotate index queue
      i5 = (int)sp[((tt + 6) & (Mc - 1)) * WRc];
    }
  }

  // Hard decision. Single-wave block: wave-synchronous, no barrier needed.
  for (int i = tid; i < 4 * Nc; i += 64) {
    const int gg = i >> 10, n = i & (Nc - 1);
    out[(size_t)(b0 + gg) * Nc + n] = (vn[n][gg] < 0.0f) ? 1.0f : 0.0f;
  }
}

extern "C" void kernel_launch(void* const* d_in, const int* in_sizes, int n_in,
                              void* d_out, int out_size, void* d_ws, size_t ws_size,
                              hipStream_t stream) {
  const float* llr = (const float*)d_in[0];
  const int* H = (const int*)d_in[1];
  const int* iters_p = (const int*)d_in[2];
  const int* cn_order = (const int*)d_in[3];
  float* out = (float*)d_out;
  build_idx<<<dim3(8), dim3(1024), 0, stream>>>(H, cn_order);
  ldpc_kernel<<<dim3(Bc / 4), dim3(64), 0, stream>>>(llr, iters_p, out);
}